// Round 2
// baseline (2123.422 us; speedup 1.0000x reference)
//
#include <hip/hip_runtime.h>

// ---------------------------------------------------------------------------
// MoE (b=4,n=2048,d=1024,dc=256,dff=4096,E=8,K=2,cap=2560).
// Input dtype (f32 vs bf16) detected at RUNTIME by a probe kernel; all
// compute runs bf16 MFMA (weights normalized to bf16 in the transpose pass).
// Pipeline: probe -> router -> bins -> [transpose weights] ->
//   GEMM1(gather+concat+gelu) -> GEMM2 -> combine.
// GEMMs: 128x128x64 tile, 4 waves, mfma_f32_16x16x32_bf16, 4x4 acc/wave.
// ---------------------------------------------------------------------------

typedef unsigned short u16;
typedef unsigned int u32;
typedef __bf16 bf16x8 __attribute__((ext_vector_type(8)));
typedef float f32x4 __attribute__((ext_vector_type(4)));

constexpr int T_TOK = 8192;
constexpr int DIM   = 1024;
constexpr int DCOND = 256;
constexpr int DFF   = 4096;
constexpr int NEXP  = 8;
constexpr int CAP   = 2560;   // int(1.25 * 2 * 8192 / 8)

__device__ __forceinline__ float b2f(u16 u) {
    union { u32 u; float f; } v; v.u = (u32)u << 16; return v.f;
}
__device__ __forceinline__ u16 f2b(float f) {
    union { float f; u32 u; } v; v.f = f;
    u32 r = (v.u + 0x7fffu + ((v.u >> 16) & 1u)) >> 16;
    return (u16)r;
}
__device__ __forceinline__ float gelu_f(float x) {
    if (!(x == x)) x = 0.f;                      // NaN-sanitize (diagnosable)
    x = fminf(1e4f, fmaxf(-1e4f, x));
    return 0.5f * x * (1.0f + tanhf(0.7978845608028654f * (x + 0.044715f * x * x * x)));
}

// ---------------------------------------------------------------------------
// Dtype probe: interpret first 4096 u16 of x. bf16 N(0,1): exponent byte
// <= ~0x84. f32 bit-halves: uniform-random exponent bytes -> ~450 hits.
// flag = 1 means inputs are float32.
// ---------------------------------------------------------------------------
__global__ void moe_probe(const u16* __restrict__ x, int* __restrict__ flag) {
    const int lane = threadIdx.x;   // 64 threads
    int cnt = 0;
    for (int i = lane; i < 4096; i += 64) {
        int e = (x[i] >> 7) & 0xFF;
        cnt += (e >= 0xC8);
    }
#pragma unroll
    for (int off = 32; off; off >>= 1) cnt += __shfl_xor(cnt, off, 64);
    if (lane == 0) flag[0] = (cnt > 8) ? 1 : 0;
}

// ---------------------------------------------------------------------------
// Router: one wave per token, f32 logits, top-2 (jax tie-break: lower index
// wins), weights = 2-way softmax.
// ---------------------------------------------------------------------------
__global__ __launch_bounds__(256) void moe_router(
    const void* __restrict__ xv, const void* __restrict__ Wrv,
    const int* __restrict__ flag,
    float* __restrict__ wbuf, int* __restrict__ idxbuf)
{
    const int t = blockIdx.x * 4 + (threadIdx.x >> 6);
    const int lane = threadIdx.x & 63;
    const bool isf32 = flag[0] != 0;

    float acc[NEXP];
#pragma unroll
    for (int e = 0; e < NEXP; ++e) acc[e] = 0.f;

    if (isf32) {
        const float* xr = (const float*)xv + (long long)t * DIM;
        const float* Wr = (const float*)Wrv;
        for (int it = 0; it < DIM / 64; ++it) {
            int d = it * 64 + lane;
            float xvv = xr[d];
            float4 wa = *(const float4*)(Wr + d * NEXP);
            float4 wb = *(const float4*)(Wr + d * NEXP + 4);
            acc[0] += xvv * wa.x; acc[1] += xvv * wa.y;
            acc[2] += xvv * wa.z; acc[3] += xvv * wa.w;
            acc[4] += xvv * wb.x; acc[5] += xvv * wb.y;
            acc[6] += xvv * wb.z; acc[7] += xvv * wb.w;
        }
    } else {
        const u16* xr = (const u16*)xv + (long long)t * DIM;
        const u16* Wr = (const u16*)Wrv;
        for (int it = 0; it < DIM / 64; ++it) {
            int d = it * 64 + lane;
            float xvv = b2f(xr[d]);
            uint4 wvv = *(const uint4*)(Wr + d * NEXP);
            const u16* ws = (const u16*)&wvv;
#pragma unroll
            for (int e = 0; e < NEXP; ++e) acc[e] += xvv * b2f(ws[e]);
        }
    }
#pragma unroll
    for (int off = 32; off; off >>= 1)
#pragma unroll
        for (int e = 0; e < NEXP; ++e) acc[e] += __shfl_xor(acc[e], off, 64);

    if (lane == 0) {
        float b1 = -3.4e38f, b2 = -3.4e38f; int i1 = 0, i2 = 0;
#pragma unroll
        for (int e = 0; e < NEXP; ++e) {
            float v = acc[e];
            if (v > b1) { b2 = b1; i2 = i1; b1 = v; i1 = e; }
            else if (v > b2) { b2 = v; i2 = e; }
        }
        float p2 = expf(b2 - b1);
        float inv = 1.0f / (1.0f + p2);
        wbuf[2 * t] = inv;       wbuf[2 * t + 1] = p2 * inv;
        idxbuf[2 * t] = i1;      idxbuf[2 * t + 1] = i2;
    }
}

// ---------------------------------------------------------------------------
// Bins: single wave, stable rank within expert == reference's stable
// argsort-by-expert + cumsum (capacity drops included).
// ---------------------------------------------------------------------------
__global__ void moe_bins(const int* __restrict__ idxbuf, int* __restrict__ slot_of,
                         int* __restrict__ token_of, int* __restrict__ rows_e)
{
    const int lane = threadIdx.x;
    const unsigned long long lmask = (1ull << lane) - 1ull;
    int cnt[NEXP];
#pragma unroll
    for (int q = 0; q < NEXP; ++q) cnt[q] = 0;

    for (int base = 0; base < T_TOK * 2; base += 256) {
        int e4[4];
#pragma unroll
        for (int u = 0; u < 4; ++u) e4[u] = idxbuf[base + u * 64 + lane];
#pragma unroll
        for (int u = 0; u < 4; ++u) {
            int e = e4[u];
            int ent = base + u * 64 + lane;
            int my = 0;
#pragma unroll
            for (int q = 0; q < NEXP; ++q) {
                unsigned long long bal = __ballot(e == q);
                if (e == q) my = cnt[q] + (int)__popcll(bal & lmask);
                cnt[q] += (int)__popcll(bal);
            }
            slot_of[ent] = my;
            if (my < CAP) token_of[e * CAP + my] = ent >> 1;
        }
    }
    if (lane == 0) {
#pragma unroll
        for (int q = 0; q < NEXP; ++q) rows_e[q] = cnt[q] < CAP ? cnt[q] : CAP;
    }
}

// ---------------------------------------------------------------------------
// Transpose [R][C] -> [C][R], OUTPUT always bf16 (normalizes dtype).
// 64x64 tiles via LDS [64][66]. z_eff = zBase + blockIdx.z selects the input
// batch (element offsets applied device-side in runtime-dtype units).
// ---------------------------------------------------------------------------
__global__ __launch_bounds__(256) void moe_transpose(
    const void* __restrict__ inv, u16* __restrict__ out, const int* __restrict__ flag,
    int R, int C, int zBase, long long inBatch, long long outBatch)
{
    const int zi = zBase + blockIdx.z;
    const bool isf32 = flag[0] != 0;
    out += (long long)blockIdx.z * outBatch;
    const int c0 = blockIdx.x * 64, r0 = blockIdx.y * 64;

    __shared__ __align__(16) u16 tile[64][66];

    for (int g = threadIdx.x; g < 512; g += 256) {
        int r = g >> 3, c8 = (g & 7) * 8;
        long long off = (long long)zi * inBatch + (long long)(r0 + r) * C + c0 + c8;
        if (isf32) {
            const float* s = (const float*)inv + off;
            float4 a = *(const float4*)s;
            float4 b = *(const float4*)(s + 4);
            tile[r][c8 + 0] = f2b(a.x); tile[r][c8 + 1] = f2b(a.y);
            tile[r][c8 + 2] = f2b(a.z); tile[r][c8 + 3] = f2b(a.w);
            tile[r][c8 + 4] = f2b(b.x); tile[r][c8 + 5] = f2b(b.y);
            tile[r][c8 + 6] = f2b(b.z); tile[r][c8 + 7] = f2b(b.w);
        } else {
            uint4 v = *(const uint4*)((const u16*)inv + off);
            const u16* s = (const u16*)&v;
#pragma unroll
            for (int j = 0; j < 8; ++j) tile[r][c8 + j] = s[j];
        }
    }
    __syncthreads();
    for (int g = threadIdx.x; g < 512; g += 256) {
        int oc = g >> 3, orr = (g & 7) * 8;
        __align__(16) u16 vals[8];
#pragma unroll
        for (int j = 0; j < 8; ++j) vals[j] = tile[orr + j][oc];
        *(uint4*)&out[(long long)(c0 + oc) * R + r0 + orr] = *(const uint4*)vals;
    }
}

// ---------------------------------------------------------------------------
// TN GEMM: C[m][n] = act( sum_k A[m][k] * BT[n][k] ), bf16 MFMA, f32 acc.
// MODE 0: dense bf16 A (GEMM2), no activation.
// MODE 1: A = concat(x,cond) by row id (shared GEMM1), gelu epilogue.
// MODE 2: A = concat(x,cond) gathered via token_of (expert GEMM1), gelu.
// MODE 1/2 read x/cond as bf16 or f32 per runtime flag.
// ---------------------------------------------------------------------------
template <int MODE, int KTOT>
__global__ __launch_bounds__(256) void moe_gemm_tn(
    const void* __restrict__ A1v, const void* __restrict__ A2v,
    const u16* __restrict__ BT, u16* __restrict__ C,
    const int* __restrict__ tok_base, const int* __restrict__ rows_base,
    const int* __restrict__ flag,
    int ldC, long long aBatch, long long bBatch, long long cBatch)
{
    static_assert(KTOT % 64 == 0, "K tile");
    const int z = blockIdx.z;
    int rows = 1 << 30;
    if (rows_base) {
        rows = rows_base[z];
        if ((int)(blockIdx.y * 128) >= rows) return;
    }
    bool isf32 = false;
    if constexpr (MODE >= 1) isf32 = flag[0] != 0;

    __shared__ __align__(16) u16 As[128 * 64];
    __shared__ __align__(16) u16 Bs[128 * 64];

    const int tid  = threadIdx.x;
    const int lane = tid & 63;
    const int wave = tid >> 6;
    const int wm = wave & 1, wn = wave >> 1;
    const int m0 = blockIdx.y * 128;
    const int n0 = blockIdx.x * 128;

    int tk[4]; int gk[4];
    const u16* aP[4]; const u16* bP[4];
#pragma unroll
    for (int i = 0; i < 4; ++i) {
        int c = tid + i * 256;
        int r = c >> 3;
        gk[i] = (c & 7) * 8;
        int rg = m0 + r;
        if constexpr (MODE == 2) {
            const int* tok = tok_base + (long long)z * CAP;
            tk[i] = (rg < rows) ? tok[rg] : 0;
        } else if constexpr (MODE == 1) {
            tk[i] = rg;
        } else {
            aP[i] = (const u16*)A1v + (long long)z * aBatch + (long long)rg * KTOT;
        }
        bP[i] = BT + (long long)z * bBatch + (long long)(n0 + r) * KTOT;
    }

    f32x4 acc[4][4];
#pragma unroll
    for (int i = 0; i < 4; ++i)
#pragma unroll
        for (int j = 0; j < 4; ++j) { f32x4 zv = {0.f, 0.f, 0.f, 0.f}; acc[i][j] = zv; }

    const int aOff = (wm * 64 + (lane & 15)) * 64 + (lane >> 4) * 8;
    const int bOff = (wn * 64 + (lane & 15)) * 64 + (lane >> 4) * 8;

    for (int k0 = 0; k0 < KTOT; k0 += 64) {
#pragma unroll
        for (int i = 0; i < 4; ++i) {
            int c = tid + i * 256;
            if constexpr (MODE >= 1) {
                int k = k0 + gk[i];
                if (!isf32) {
                    const u16* pa = (k < DIM)
                        ? (const u16*)A1v + (long long)tk[i] * DIM + k
                        : (const u16*)A2v + (long long)tk[i] * DCOND + (k - DIM);
                    *(uint4*)&As[8 * c] = *(const uint4*)pa;
                } else {
                    const float* pa = (k < DIM)
                        ? (const float*)A1v + (long long)tk[i] * DIM + k
                        : (const float*)A2v + (long long)tk[i] * DCOND + (k - DIM);
                    float4 a = *(const float4*)pa;
                    float4 b = *(const float4*)(pa + 4);
                    __align__(16) u16 t8[8];
                    t8[0] = f2b(a.x); t8[1] = f2b(a.y); t8[2] = f2b(a.z); t8[3] = f2b(a.w);
                    t8[4] = f2b(b.x); t8[5] = f2b(b.y); t8[6] = f2b(b.z); t8[7] = f2b(b.w);
                    *(uint4*)&As[8 * c] = *(const uint4*)t8;
                }
            } else {
                *(uint4*)&As[8 * c] = *(const uint4*)(aP[i] + k0 + gk[i]);
            }
            *(uint4*)&Bs[8 * c] = *(const uint4*)(bP[i] + k0 + gk[i]);
        }
        __syncthreads();
#pragma unroll
        for (int ks = 0; ks < 64; ks += 32) {
            bf16x8 af[4], bf[4];
#pragma unroll
            for (int i = 0; i < 4; ++i) af[i] = *(const bf16x8*)&As[aOff + i * 16 * 64 + ks];
#pragma unroll
            for (int j = 0; j < 4; ++j) bf[j] = *(const bf16x8*)&Bs[bOff + j * 16 * 64 + ks];
#pragma unroll
            for (int i = 0; i < 4; ++i)
#pragma unroll
                for (int j = 0; j < 4; ++j)
                    acc[i][j] = __builtin_amdgcn_mfma_f32_16x16x32_bf16(af[i], bf[j], acc[i][j], 0, 0, 0);
        }
        __syncthreads();
    }

    // C/D layout: col=lane&15, row=(lane>>4)*4+reg (m89/m91-verified).
#pragma unroll
    for (int i = 0; i < 4; ++i) {
        int orow_b = wm * 64 + i * 16 + (lane >> 4) * 4;
#pragma unroll
        for (int j = 0; j < 4; ++j) {
            int ocol = n0 + wn * 64 + j * 16 + (lane & 15);
#pragma unroll
            for (int r = 0; r < 4; ++r) {
                float v = acc[i][j][r];
                if constexpr (MODE >= 1) v = gelu_f(v);
                long long orow = m0 + orow_b + r;
                C[(long long)z * cBatch + orow * ldC + ocol] = f2b(v);
            }
        }
    }
}

// ---------------------------------------------------------------------------
// Combine: out[t] = mask[t]*(xs[t] + 2*(w1*v1*y[e1,p1] + w2*v2*y[e2,p2]))/3
// Output dtype follows the runtime flag.
// ---------------------------------------------------------------------------
__global__ __launch_bounds__(256) void moe_combine(
    const u16* __restrict__ xs, const u16* __restrict__ y,
    const float* __restrict__ wbuf, const int* __restrict__ idxbuf,
    const int* __restrict__ slot_of, const void* __restrict__ maskv,
    void* __restrict__ outv, const int* __restrict__ flag)
{
    const int t = blockIdx.x;
    const int c = threadIdx.x * 4;
    const bool isf32 = flag[0] != 0;
    const float mk = isf32 ? ((const float*)maskv)[t] : b2f(((const u16*)maskv)[t]);

    int e1 = idxbuf[2 * t], e2 = idxbuf[2 * t + 1];
    int s1 = slot_of[2 * t], s2 = slot_of[2 * t + 1];
    float w1 = wbuf[2 * t], w2 = wbuf[2 * t + 1];
    float g1 = (s1 < CAP) ? w1 : 0.f;
    float g2 = (s2 < CAP) ? w2 : 0.f;
    int r1 = s1 < CAP ? s1 : CAP - 1;
    int r2 = s2 < CAP ? s2 : CAP - 1;

    uint2 xvv = *(const uint2*)(xs + (long long)t * DIM + c);
    uint2 y1 = *(const uint2*)(y + ((long long)e1 * CAP + r1) * DIM + c);
    uint2 y2 = *(const uint2*)(y + ((long long)e2 * CAP + r2) * DIM + c);
    const u16* xp = (const u16*)&xvv;
    const u16* p1 = (const u16*)&y1;
    const u16* p2 = (const u16*)&y2;

    float o[4];
#pragma unroll
    for (int q = 0; q < 4; ++q) {
        float v = (b2f(xp[q]) + 2.f * (g1 * b2f(p1[q]) + g2 * b2f(p2[q]))) * mk * (1.f / 3.f);
        o[q] = (v == v) ? v : 0.f;
    }
    if (isf32) {
        float4 o4 = {o[0], o[1], o[2], o[3]};
        *(float4*)((float*)outv + (long long)t * DIM + c) = o4;
    } else {
        __align__(8) u16 ov[4];
#pragma unroll
        for (int q = 0; q < 4; ++q) ov[q] = f2b(o[q]);
        *(uint2*)((u16*)outv + (long long)t * DIM + c) = *(const uint2*)ov;
    }
}

// ---------------------------------------------------------------------------
extern "C" void kernel_launch(void* const* d_in, const int* in_sizes, int n_in,
                              void* d_out, int out_size, void* d_ws, size_t ws_size,
                              hipStream_t stream)
{
    const void* x    = d_in[0];
    const void* cond = d_in[1];
    const void* mask = d_in[2];
    const void* Wr   = d_in[3];
    const void* W1s  = d_in[4];
    const void* W2s  = d_in[5];
    const void* W1e  = d_in[6];
    const void* W2e  = d_in[7];

    const int KIN = DIM + DCOND;   // 1280

    // Workspace carve (~237.3 MB; proven mapped in round 1).
    char* p = (char*)d_ws;
    u16* W1sT   = (u16*)p; p += (long long)DFF * KIN * 2;
    u16* W2sT   = (u16*)p; p += (long long)DIM * DFF * 2;
    u16* W1eT4  = (u16*)p; p += 4LL * DFF * KIN * 2;
    u16* W2eT4  = (u16*)p; p += 4LL * DIM * DFF * 2;
    u16* h      = (u16*)p; p += 4LL * CAP * DFF * 2;               // >= 8192*4096
    u16* xs     = (u16*)p; p += (long long)T_TOK * DIM * 2;
    u16* y      = (u16*)p; p += (long long)NEXP * CAP * DIM * 2;
    float* wbuf = (float*)p; p += T_TOK * 2 * sizeof(float);
    int* idxbuf = (int*)p;   p += T_TOK * 2 * sizeof(int);
    int* slot_of = (int*)p;  p += T_TOK * 2 * sizeof(int);
    int* token_of = (int*)p; p += NEXP * CAP * sizeof(int);
    int* rows_e = (int*)p;   p += 256;
    int* flag   = (int*)p;   p += 256;
    (void)ws_size; (void)in_sizes; (void)n_in; (void)out_size;

    dim3 b256(256);

    moe_probe<<<dim3(1), dim3(64), 0, stream>>>((const u16*)x, flag);
    moe_router<<<dim3(T_TOK / 4), b256, 0, stream>>>(x, Wr, flag, wbuf, idxbuf);
    moe_bins<<<dim3(1), dim3(64), 0, stream>>>(idxbuf, slot_of, token_of, rows_e);

    moe_transpose<<<dim3(DFF / 64, KIN / 64, 1), b256, 0, stream>>>(
        W1s, W1sT, flag, KIN, DFF, 0, 0, 0);
    moe_transpose<<<dim3(DIM / 64, DFF / 64, 1), b256, 0, stream>>>(
        W2s, W2sT, flag, DFF, DIM, 0, 0, 0);

    // Shared expert: h = gelu([x|cond] @ W1s); xs = h @ W2s.
    moe_gemm_tn<1, 1280><<<dim3(DFF / 128, T_TOK / 128, 1), b256, 0, stream>>>(
        x, cond, W1sT, h, nullptr, nullptr, flag, DFF, 0, 0, 0);
    moe_gemm_tn<0, 4096><<<dim3(DIM / 128, T_TOK / 128, 1), b256, 0, stream>>>(
        h, nullptr, W2sT, xs, nullptr, nullptr, flag, DIM, 0, 0, 0);

    // Routed experts, 2 groups of 4 (z-batched; zBase applies the group
    // offset in element units of the runtime dtype).
    for (int g = 0; g < 2; ++g) {
        moe_transpose<<<dim3(DFF / 64, KIN / 64, 4), b256, 0, stream>>>(
            W1e, W1eT4, flag, KIN, DFF, g * 4,
            (long long)KIN * DFF, (long long)DFF * KIN);
        moe_transpose<<<dim3(DIM / 64, DFF / 64, 4), b256, 0, stream>>>(
            W2e, W2eT4, flag, DFF, DIM, g * 4,
            (long long)DFF * DIM, (long long)DIM * DFF);

        moe_gemm_tn<2, 1280><<<dim3(DFF / 128, CAP / 128, 4), b256, 0, stream>>>(
            x, cond, W1eT4, h, token_of + g * 4 * CAP, rows_e + g * 4, flag,
            DFF, 0, (long long)DFF * KIN, (long long)CAP * DFF);
        moe_gemm_tn<0, 4096><<<dim3(DIM / 128, CAP / 128, 4), b256, 0, stream>>>(
            h, nullptr, W2eT4, y + (long long)g * 4 * CAP * DIM, nullptr, rows_e + g * 4, flag,
            DIM, (long long)CAP * DFF, (long long)DIM * DFF, (long long)CAP * DIM);
    }

    moe_combine<<<dim3(T_TOK), b256, 0, stream>>>(xs, y, wbuf, idxbuf, slot_of, mask, d_out, flag);
}

// Round 3
// 1576.635 us; speedup vs baseline: 1.3468x; 1.3468x over previous
//
#include <hip/hip_runtime.h>

// ---------------------------------------------------------------------------
// MoE (b=4,n=2048,d=1024,dc=256,dff=4096,E=8,K=2,cap=2560). Inputs f32 or
// bf16 (runtime probe; round-2 bench proved f32). Pipeline:
//   probe -> cvt(x,cond->bf16) -> router(f32 path) -> bins ->
//   [transpose weights (->bf16)] -> GEMM1(gather+concat+gelu) -> GEMM2 ->
//   combine.
// GEMMs: 128x128x64 tile, 4 waves, mfma_f32_16x16x32_bf16, 4x4 acc/wave,
// global_load_lds width=16 staging for BOTH A and B (m97 structure).
// ---------------------------------------------------------------------------

typedef unsigned short u16;
typedef unsigned int u32;
typedef __bf16 bf16x8 __attribute__((ext_vector_type(8)));
typedef float f32x4 __attribute__((ext_vector_type(4)));

constexpr int T_TOK = 8192;
constexpr int DIM   = 1024;
constexpr int DCOND = 256;
constexpr int DFF   = 4096;
constexpr int NEXP  = 8;
constexpr int CAP   = 2560;   // int(1.25 * 2 * 8192 / 8)

__device__ __forceinline__ float b2f(u16 u) {
    union { u32 u; float f; } v; v.u = (u32)u << 16; return v.f;
}
__device__ __forceinline__ u16 f2b(float f) {
    union { float f; u32 u; } v; v.f = f;
    u32 r = (v.u + 0x7fffu + ((v.u >> 16) & 1u)) >> 16;
    return (u16)r;
}
__device__ __forceinline__ float gelu_f(float x) {
    if (!(x == x)) x = 0.f;
    x = fminf(1e4f, fmaxf(-1e4f, x));
    return 0.5f * x * (1.0f + tanhf(0.7978845608028654f * (x + 0.044715f * x * x * x)));
}

// global -> LDS DMA, 16 B per lane; LDS dest is wave-uniform base + lane*16.
__device__ __forceinline__ void gload16(const u16* g, u16* l) {
    __builtin_amdgcn_global_load_lds(
        (const __attribute__((address_space(1))) void*)g,
        (__attribute__((address_space(3))) void*)l, 16, 0, 0);
}

// ---------------------------------------------------------------------------
// Dtype probe: flag=1 means inputs are float32 (round 2 measured: they are).
// ---------------------------------------------------------------------------
__global__ void moe_probe(const u16* __restrict__ x, int* __restrict__ flag) {
    const int lane = threadIdx.x;   // 64 threads
    int cnt = 0;
    for (int i = lane; i < 4096; i += 64) {
        int e = (x[i] >> 7) & 0xFF;
        cnt += (e >= 0xC8);
    }
#pragma unroll
    for (int off = 32; off; off >>= 1) cnt += __shfl_xor(cnt, off, 64);
    if (lane == 0) flag[0] = (cnt > 8) ? 1 : 0;
}

// ---------------------------------------------------------------------------
// cvt: normalize a tensor to bf16 (straight copy if already bf16).
// 8 elements per thread, exact-size grid.
// ---------------------------------------------------------------------------
__global__ __launch_bounds__(256) void moe_cvt(
    const void* __restrict__ in, u16* __restrict__ out,
    const int* __restrict__ flag)
{
    const long long i = ((long long)blockIdx.x * 256 + threadIdx.x) * 8;
    if (flag[0]) {
        const float* s = (const float*)in + i;
        float4 a = *(const float4*)s;
        float4 b = *(const float4*)(s + 4);
        __align__(16) u16 t8[8];
        t8[0] = f2b(a.x); t8[1] = f2b(a.y); t8[2] = f2b(a.z); t8[3] = f2b(a.w);
        t8[4] = f2b(b.x); t8[5] = f2b(b.y); t8[6] = f2b(b.z); t8[7] = f2b(b.w);
        *(uint4*)(out + i) = *(const uint4*)t8;
    } else {
        *(uint4*)(out + i) = *(const uint4*)((const u16*)in + i);
    }
}

// ---------------------------------------------------------------------------
// Router: one wave per token, f32 logits (reads ORIGINAL x so top-k ties
// match the f32 reference), top-2 lower-index-wins, 2-way softmax weights.
// ---------------------------------------------------------------------------
__global__ __launch_bounds__(256) void moe_router(
    const void* __restrict__ xv, const void* __restrict__ Wrv,
    const int* __restrict__ flag,
    float* __restrict__ wbuf, int* __restrict__ idxbuf)
{
    const int t = blockIdx.x * 4 + (threadIdx.x >> 6);
    const int lane = threadIdx.x & 63;
    const bool isf32 = flag[0] != 0;

    float acc[NEXP];
#pragma unroll
    for (int e = 0; e < NEXP; ++e) acc[e] = 0.f;

    if (isf32) {
        const float* xr = (const float*)xv + (long long)t * DIM;
        const float* Wr = (const float*)Wrv;
        for (int it = 0; it < DIM / 64; ++it) {
            int d = it * 64 + lane;
            float xvv = xr[d];
            float4 wa = *(const float4*)(Wr + d * NEXP);
            float4 wb = *(const float4*)(Wr + d * NEXP + 4);
            acc[0] += xvv * wa.x; acc[1] += xvv * wa.y;
            acc[2] += xvv * wa.z; acc[3] += xvv * wa.w;
            acc[4] += xvv * wb.x; acc[5] += xvv * wb.y;
            acc[6] += xvv * wb.z; acc[7] += xvv * wb.w;
        }
    } else {
        const u16* xr = (const u16*)xv + (long long)t * DIM;
        const u16* Wr = (const u16*)Wrv;
        for (int it = 0; it < DIM / 64; ++it) {
            int d = it * 64 + lane;
            float xvv = b2f(xr[d]);
            uint4 wvv = *(const uint4*)(Wr + d * NEXP);
            const u16* ws = (const u16*)&wvv;
#pragma unroll
            for (int e = 0; e < NEXP; ++e) acc[e] += xvv * b2f(ws[e]);
        }
    }
#pragma unroll
    for (int off = 32; off; off >>= 1)
#pragma unroll
        for (int e = 0; e < NEXP; ++e) acc[e] += __shfl_xor(acc[e], off, 64);

    if (lane == 0) {
        float b1 = -3.4e38f, b2 = -3.4e38f; int i1 = 0, i2 = 0;
#pragma unroll
        for (int e = 0; e < NEXP; ++e) {
            float v = acc[e];
            if (v > b1) { b2 = b1; i2 = i1; b1 = v; i1 = e; }
            else if (v > b2) { b2 = v; i2 = e; }
        }
        float p2 = expf(b2 - b1);
        float inv = 1.0f / (1.0f + p2);
        wbuf[2 * t] = inv;       wbuf[2 * t + 1] = p2 * inv;
        idxbuf[2 * t] = i1;      idxbuf[2 * t + 1] = i2;
    }
}

// ---------------------------------------------------------------------------
// Bins: single wave, stable rank within expert == reference stable argsort.
// ---------------------------------------------------------------------------
__global__ void moe_bins(const int* __restrict__ idxbuf, int* __restrict__ slot_of,
                         int* __restrict__ token_of, int* __restrict__ rows_e)
{
    const int lane = threadIdx.x;
    const unsigned long long lmask = (1ull << lane) - 1ull;
    int cnt[NEXP];
#pragma unroll
    for (int q = 0; q < NEXP; ++q) cnt[q] = 0;

    for (int base = 0; base < T_TOK * 2; base += 256) {
        int e4[4];
#pragma unroll
        for (int u = 0; u < 4; ++u) e4[u] = idxbuf[base + u * 64 + lane];
#pragma unroll
        for (int u = 0; u < 4; ++u) {
            int e = e4[u];
            int ent = base + u * 64 + lane;
            int my = 0;
#pragma unroll
            for (int q = 0; q < NEXP; ++q) {
                unsigned long long bal = __ballot(e == q);
                if (e == q) my = cnt[q] + (int)__popcll(bal & lmask);
                cnt[q] += (int)__popcll(bal);
            }
            slot_of[ent] = my;
            if (my < CAP) token_of[e * CAP + my] = ent >> 1;
        }
    }
    if (lane == 0) {
#pragma unroll
        for (int q = 0; q < NEXP; ++q) rows_e[q] = cnt[q] < CAP ? cnt[q] : CAP;
    }
}

// ---------------------------------------------------------------------------
// Transpose [R][C] -> [C][R], output always bf16. z_eff = zBase + blockIdx.z
// selects input batch (element units of the runtime dtype).
// ---------------------------------------------------------------------------
__global__ __launch_bounds__(256) void moe_transpose(
    const void* __restrict__ inv, u16* __restrict__ out, const int* __restrict__ flag,
    int R, int C, int zBase, long long inBatch, long long outBatch)
{
    const int zi = zBase + blockIdx.z;
    const bool isf32 = flag[0] != 0;
    out += (long long)blockIdx.z * outBatch;
    const int c0 = blockIdx.x * 64, r0 = blockIdx.y * 64;

    __shared__ __align__(16) u16 tile[64][66];

    for (int g = threadIdx.x; g < 512; g += 256) {
        int r = g >> 3, c8 = (g & 7) * 8;
        long long off = (long long)zi * inBatch + (long long)(r0 + r) * C + c0 + c8;
        if (isf32) {
            const float* s = (const float*)inv + off;
            float4 a = *(const float4*)s;
            float4 b = *(const float4*)(s + 4);
            tile[r][c8 + 0] = f2b(a.x); tile[r][c8 + 1] = f2b(a.y);
            tile[r][c8 + 2] = f2b(a.z); tile[r][c8 + 3] = f2b(a.w);
            tile[r][c8 + 4] = f2b(b.x); tile[r][c8 + 5] = f2b(b.y);
            tile[r][c8 + 6] = f2b(b.z); tile[r][c8 + 7] = f2b(b.w);
        } else {
            uint4 v = *(const uint4*)((const u16*)inv + off);
            const u16* s = (const u16*)&v;
#pragma unroll
            for (int j = 0; j < 8; ++j) tile[r][c8 + j] = s[j];
        }
    }
    __syncthreads();
    for (int g = threadIdx.x; g < 512; g += 256) {
        int oc = g >> 3, orr = (g & 7) * 8;
        __align__(16) u16 vals[8];
#pragma unroll
        for (int j = 0; j < 8; ++j) vals[j] = tile[orr + j][oc];
        *(uint4*)&out[(long long)(c0 + oc) * R + r0 + orr] = *(const uint4*)vals;
    }
}

// ---------------------------------------------------------------------------
// TN GEMM: C[m][n] = act( sum_k A[m][k] * BT[n][k] ), pure bf16, f32 acc.
// MODE 0: dense A (GEMM2), no activation.
// MODE 1: A = concat(xb,cb) by row id (shared GEMM1), gelu epilogue.
// MODE 2: A = concat(xb,cb) gathered via token_of (expert GEMM1), gelu.
// Staging: global_load_lds width=16 for A and B (LDS dest is wave-uniform
// base + lane*16 -> As layout 8*c with c=tid+i*256 is exactly lane order).
// ---------------------------------------------------------------------------
template <int MODE, int KTOT>
__global__ __launch_bounds__(256) void moe_gemm_tn(
    const u16* __restrict__ A1, const u16* __restrict__ A2,
    const u16* __restrict__ BT, u16* __restrict__ C,
    const int* __restrict__ tok_base, const int* __restrict__ rows_base,
    int ldC, long long aBatch, long long bBatch, long long cBatch)
{
    static_assert(KTOT % 64 == 0, "K tile");
    const int z = blockIdx.z;
    int rows = 1 << 30;
    if (rows_base) {
        rows = rows_base[z];
        if ((int)(blockIdx.y * 128) >= rows) return;
    }

    __shared__ __align__(16) u16 As[128 * 64];
    __shared__ __align__(16) u16 Bs[128 * 64];

    const int tid  = threadIdx.x;
    const int lane = tid & 63;
    const int wave = tid >> 6;
    const int wm = wave & 1, wn = wave >> 1;
    const int m0 = blockIdx.y * 128;
    const int n0 = blockIdx.x * 128;

    // Per-thread staging pointers: 4 granules (16B) of A and of B.
    const u16* pA1[4]; const u16* pA2[4]; const u16* bP[4];
#pragma unroll
    for (int i = 0; i < 4; ++i) {
        int c = tid + i * 256;
        int r = c >> 3;
        int gk = (c & 7) * 8;
        int rg = m0 + r;
        if constexpr (MODE == 2) {
            const int* tok = tok_base + (long long)z * CAP;
            int tk = (rg < rows) ? tok[rg] : 0;  // guard: slots >= count are poison
            pA1[i] = A1 + (long long)tk * DIM + gk;
            pA2[i] = A2 + (long long)tk * DCOND + gk - DIM;
        } else if constexpr (MODE == 1) {
            pA1[i] = A1 + (long long)rg * DIM + gk;
            pA2[i] = A2 + (long long)rg * DCOND + gk - DIM;
        } else {
            pA1[i] = A1 + (long long)z * aBatch + (long long)rg * KTOT + gk;
        }
        bP[i] = BT + (long long)z * bBatch + (long long)(n0 + r) * KTOT + gk;
    }

    f32x4 acc[4][4];
#pragma unroll
    for (int i = 0; i < 4; ++i)
#pragma unroll
        for (int j = 0; j < 4; ++j) { f32x4 zv = {0.f, 0.f, 0.f, 0.f}; acc[i][j] = zv; }

    const int aOff = (wm * 64 + (lane & 15)) * 64 + (lane >> 4) * 8;
    const int bOff = (wn * 64 + (lane & 15)) * 64 + (lane >> 4) * 8;

    for (int k0 = 0; k0 < KTOT; k0 += 64) {
#pragma unroll
        for (int i = 0; i < 4; ++i) {
            const int ldsOff = 8 * (i * 256 + wave * 64);  // wave-uniform
            const u16* ga;
            if constexpr (MODE >= 1) {
                ga = (k0 < DIM) ? pA1[i] + k0 : pA2[i] + k0;  // BK|DIM -> uniform select
            } else {
                ga = pA1[i] + k0;
            }
            gload16(ga, &As[ldsOff]);
            gload16(bP[i] + k0, &Bs[ldsOff]);
        }
        __syncthreads();
#pragma unroll
        for (int ks = 0; ks < 64; ks += 32) {
            bf16x8 af[4], bf[4];
#pragma unroll
            for (int i = 0; i < 4; ++i) af[i] = *(const bf16x8*)&As[aOff + i * 16 * 64 + ks];
#pragma unroll
            for (int j = 0; j < 4; ++j) bf[j] = *(const bf16x8*)&Bs[bOff + j * 16 * 64 + ks];
#pragma unroll
            for (int i = 0; i < 4; ++i)
#pragma unroll
                for (int j = 0; j < 4; ++j)
                    acc[i][j] = __builtin_amdgcn_mfma_f32_16x16x32_bf16(af[i], bf[j], acc[i][j], 0, 0, 0);
        }
        __syncthreads();
    }

    // C/D layout: col=lane&15, row=(lane>>4)*4+reg (m89/m91-verified).
#pragma unroll
    for (int i = 0; i < 4; ++i) {
        int orow_b = wm * 64 + i * 16 + (lane >> 4) * 4;
#pragma unroll
        for (int j = 0; j < 4; ++j) {
            int ocol = n0 + wn * 64 + j * 16 + (lane & 15);
#pragma unroll
            for (int r = 0; r < 4; ++r) {
                float v = acc[i][j][r];
                if constexpr (MODE >= 1) v = gelu_f(v);
                long long orow = m0 + orow_b + r;
                C[(long long)z * cBatch + orow * ldC + ocol] = f2b(v);
            }
        }
    }
}

// ---------------------------------------------------------------------------
// Combine: out[t] = mask[t]*(xs[t] + 2*(w1*v1*y[e1,p1] + w2*v2*y[e2,p2]))/3
// ---------------------------------------------------------------------------
__global__ __launch_bounds__(256) void moe_combine(
    const u16* __restrict__ xs, const u16* __restrict__ y,
    const float* __restrict__ wbuf, const int* __restrict__ idxbuf,
    const int* __restrict__ slot_of, const void* __restrict__ maskv,
    void* __restrict__ outv, const int* __restrict__ flag)
{
    const int t = blockIdx.x;
    const int c = threadIdx.x * 4;
    const bool isf32 = flag[0] != 0;
    const float mk = isf32 ? ((const float*)maskv)[t] : b2f(((const u16*)maskv)[t]);

    int e1 = idxbuf[2 * t], e2 = idxbuf[2 * t + 1];
    int s1 = slot_of[2 * t], s2 = slot_of[2 * t + 1];
    float w1 = wbuf[2 * t], w2 = wbuf[2 * t + 1];
    float g1 = (s1 < CAP) ? w1 : 0.f;
    float g2 = (s2 < CAP) ? w2 : 0.f;
    int r1 = s1 < CAP ? s1 : CAP - 1;
    int r2 = s2 < CAP ? s2 : CAP - 1;

    uint2 xvv = *(const uint2*)(xs + (long long)t * DIM + c);
    uint2 y1 = *(const uint2*)(y + ((long long)e1 * CAP + r1) * DIM + c);
    uint2 y2 = *(const uint2*)(y + ((long long)e2 * CAP + r2) * DIM + c);
    const u16* xp = (const u16*)&xvv;
    const u16* p1 = (const u16*)&y1;
    const u16* p2 = (const u16*)&y2;

    float o[4];
#pragma unroll
    for (int q = 0; q < 4; ++q) {
        float v = (b2f(xp[q]) + 2.f * (g1 * b2f(p1[q]) + g2 * b2f(p2[q]))) * mk * (1.f / 3.f);
        o[q] = (v == v) ? v : 0.f;
    }
    if (isf32) {
        float4 o4 = {o[0], o[1], o[2], o[3]};
        *(float4*)((float*)outv + (long long)t * DIM + c) = o4;
    } else {
        __align__(8) u16 ov[4];
#pragma unroll
        for (int q = 0; q < 4; ++q) ov[q] = f2b(o[q]);
        *(uint2*)((u16*)outv + (long long)t * DIM + c) = *(const uint2*)ov;
    }
}

// ---------------------------------------------------------------------------
extern "C" void kernel_launch(void* const* d_in, const int* in_sizes, int n_in,
                              void* d_out, int out_size, void* d_ws, size_t ws_size,
                              hipStream_t stream)
{
    const void* x    = d_in[0];
    const void* cond = d_in[1];
    const void* mask = d_in[2];
    const void* Wr   = d_in[3];
    const void* W1s  = d_in[4];
    const void* W2s  = d_in[5];
    const void* W1e  = d_in[6];
    const void* W2e  = d_in[7];

    const int KIN = DIM + DCOND;   // 1280
    const int EG  = 2;             // experts per group (bounds workspace)

    // Workspace carve (~194 MB; round-1/2 proved >=237 MB mapped).
    char* p = (char*)d_ws;
    u16* W1sT   = (u16*)p; p += (long long)DFF * KIN * 2;          // 10.5 MB
    u16* W2sT   = (u16*)p; p += (long long)DIM * DFF * 2;          //  8.4 MB
    u16* W1eT   = (u16*)p; p += (long long)EG * DFF * KIN * 2;     // 21.0 MB
    u16* W2eT   = (u16*)p; p += (long long)EG * DIM * DFF * 2;     // 16.8 MB
    u16* h      = (u16*)p; p += (long long)T_TOK * DFF * 2;        // 67.1 MB (>= EG*CAP*DFF)
    u16* xs     = (u16*)p; p += (long long)T_TOK * DIM * 2;        // 16.8 MB
    u16* y      = (u16*)p; p += (long long)NEXP * CAP * DIM * 2;   // 41.9 MB
    u16* xb     = (u16*)p; p += (long long)T_TOK * DIM * 2;        // 16.8 MB
    u16* cb     = (u16*)p; p += (long long)T_TOK * DCOND * 2;      //  4.2 MB
    float* wbuf = (float*)p; p += T_TOK * 2 * sizeof(float);
    int* idxbuf = (int*)p;   p += T_TOK * 2 * sizeof(int);
    int* slot_of = (int*)p;  p += T_TOK * 2 * sizeof(int);
    int* token_of = (int*)p; p += NEXP * CAP * sizeof(int);
    int* rows_e = (int*)p;   p += 256;
    int* flag   = (int*)p;   p += 256;
    (void)ws_size; (void)in_sizes; (void)n_in; (void)out_size;

    dim3 b256(256);

    moe_probe<<<dim3(1), dim3(64), 0, stream>>>((const u16*)x, flag);

    // Normalize activations to bf16 once (GEMMs become single-path DMA).
    moe_cvt<<<dim3(T_TOK * DIM / (256 * 8)), b256, 0, stream>>>(x, xb, flag);
    moe_cvt<<<dim3(T_TOK * DCOND / (256 * 8)), b256, 0, stream>>>(cond, cb, flag);

    moe_router<<<dim3(T_TOK / 4), b256, 0, stream>>>(x, Wr, flag, wbuf, idxbuf);
    moe_bins<<<dim3(1), dim3(64), 0, stream>>>(idxbuf, slot_of, token_of, rows_e);

    moe_transpose<<<dim3(DFF / 64, KIN / 64, 1), b256, 0, stream>>>(
        W1s, W1sT, flag, KIN, DFF, 0, 0, 0);
    moe_transpose<<<dim3(DIM / 64, DFF / 64, 1), b256, 0, stream>>>(
        W2s, W2sT, flag, DFF, DIM, 0, 0, 0);

    // Shared expert: h = gelu([xb|cb] @ W1s); xs = h @ W2s.
    moe_gemm_tn<1, 1280><<<dim3(DFF / 128, T_TOK / 128, 1), b256, 0, stream>>>(
        xb, cb, W1sT, h, nullptr, nullptr, DFF, 0, 0, 0);
    moe_gemm_tn<0, 4096><<<dim3(DIM / 128, T_TOK / 128, 1), b256, 0, stream>>>(
        h, nullptr, W2sT, xs, nullptr, nullptr, DIM, 0, 0, 0);

    // Routed experts, 4 groups of EG=2 (z-batched).
    for (int g = 0; g < NEXP / EG; ++g) {
        moe_transpose<<<dim3(DFF / 64, KIN / 64, EG), b256, 0, stream>>>(
            W1e, W1eT, flag, KIN, DFF, g * EG,
            (long long)KIN * DFF, (long long)DFF * KIN);
        moe_transpose<<<dim3(DIM / 64, DFF / 64, EG), b256, 0, stream>>>(
            W2e, W2eT, flag, DFF, DIM, g * EG,
            (long long)DFF * DIM, (long long)DIM * DFF);

        moe_gemm_tn<2, 1280><<<dim3(DFF / 128, CAP / 128, EG), b256, 0, stream>>>(
            xb, cb, W1eT, h, token_of + g * EG * CAP, rows_e + g * EG,
            DFF, 0, (long long)DFF * KIN, (long long)CAP * DFF);
        moe_gemm_tn<0, 4096><<<dim3(DIM / 128, CAP / 128, EG), b256, 0, stream>>>(
            h, nullptr, W2eT, y + (long long)g * EG * CAP * DIM, nullptr, rows_e + g * EG,
            DIM, (long long)CAP * DFF, (long long)DIM * DFF, (long long)CAP * DIM);
    }

    moe_combine<<<dim3(T_TOK), b256, 0, stream>>>(xs, y, wbuf, idxbuf, slot_of, mask, d_out, flag);
}